// Round 2
// baseline (4538.571 us; speedup 1.0000x reference)
//
#include <hip/hip_runtime.h>
#include <math.h>

#define LL  12
#define BB  8
#define HH  12
#define CTX 2048
#define DD  64
#define EE  768
#define N3E 2304
#define N4E 3072
#define VV  50257
#define TCH 128
#define NCH 16   // CTX / TCH

__device__ __forceinline__ float wave_reduce_sum(float v){
  #pragma unroll
  for(int off = 32; off; off >>= 1) v += __shfl_xor(v, off);
  return v;
}
__device__ __forceinline__ float wave_reduce_max(float v){
  #pragma unroll
  for(int off = 32; off; off >>= 1) v = fmaxf(v, __shfl_xor(v, off));
  return v;
}

// ---------------- embedding: h[b,:] = wte[id_b,:] + wpe[past,:] ----------------
__global__ __launch_bounds__(256) void embed_k(const int* __restrict__ ids,
                                               const float* __restrict__ wte,
                                               const float* __restrict__ wpe,
                                               const int* __restrict__ past_p,
                                               float* __restrict__ h){
  const int b = blockIdx.x;
  const int pos = *past_p;
  const int id = ids[b];
  for(int e = threadIdx.x; e < EE; e += 256)
    h[b*EE + e] = wte[(size_t)id*EE + e] + wpe[(size_t)pos*EE + e];
}

// ---- one-shot bias pre-init for ALL layers: qkv_all[l][b][:] = attn_b[l][:], u_all likewise ----
__global__ __launch_bounds__(256) void prep_all_k(const float* __restrict__ ab,
                                                  const float* __restrict__ fb,
                                                  float* __restrict__ qkv_all,
                                                  float* __restrict__ u_all){
  const int i = blockIdx.x*256 + threadIdx.x;   // 0 .. 516096
  if(i < LL*BB*N3E){
    qkv_all[i] = ab[(i/(BB*N3E))*N3E + (i % N3E)];
  } else {
    const int k = i - LL*BB*N3E;                // 0 .. 294912
    u_all[k] = fb[(k/(BB*N4E))*N4E + (k % N4E)];
  }
}

// block-level LN stats for all 8 rows of h (E=768). 256 thr: b = tid>>5, 32 lanes/b.
__device__ __forceinline__ void ln_stats(const float* __restrict__ h,
                                         float* mean_s, float* rstd_s){
  const int tid = threadIdx.x;
  const int b = tid >> 5;
  const int l32 = tid & 31;
  const float* row = h + b*EE;
  float s = 0.f, ss = 0.f;
  #pragma unroll
  for(int i = 0; i < 24; ++i){          // 768/32 = 24 per lane
    float x = row[l32*24 + i];
    s += x; ss += x*x;
  }
  #pragma unroll
  for(int off = 16; off; off >>= 1){ s += __shfl_xor(s, off); ss += __shfl_xor(ss, off); }
  if(l32 == 0){
    const float m = s * (1.f/EE);
    const float var = ss*(1.f/EE) - m*m;
    mean_s[b] = m;
    rstd_s[b] = rsqrtf(var + 1e-5f);
  }
}

// out[b,j] += LN(h)[b, e0:e0+64] @ W[e0:e0+64, j]   (atomic; out pre-init'd with bias)
__global__ __launch_bounds__(256) void ln_gemv_k(const float* __restrict__ h,
                                                 const float* __restrict__ g,
                                                 const float* __restrict__ beta,
                                                 const float* __restrict__ W,
                                                 float* __restrict__ out, int N){
  __shared__ float mean_s[BB], rstd_s[BB];
  __shared__ float x_s[BB*64];
  const int tid = threadIdx.x;
  ln_stats(h, mean_s, rstd_s);
  __syncthreads();
  const int e0 = blockIdx.y * 64;
  for(int i = tid; i < BB*64; i += 256){
    const int b = i >> 6, e = i & 63;
    const float x = (h[b*EE + e0 + e] - mean_s[b]) * rstd_s[b];
    x_s[i] = x * g[e0+e] + beta[e0+e];
  }
  __syncthreads();
  const int j = blockIdx.x*256 + tid;
  float acc[BB] = {0,0,0,0,0,0,0,0};
  const float* Wc = W + (size_t)e0 * N + j;
  #pragma unroll 4
  for(int e = 0; e < 64; ++e){
    const float w = Wc[(size_t)e*N];
    #pragma unroll
    for(int b = 0; b < BB; ++b) acc[b] += x_s[b*64+e] * w;
  }
  #pragma unroll
  for(int b = 0; b < BB; ++b) atomicAdd(&out[b*N + j], acc[b]);
}

// out[b,j] += gelu?(in)[b, e0:e0+64] @ W[e0:e0+64, j] (+ bias if y==0). out = residual h.
__global__ __launch_bounds__(256) void gemv_acc_k(const float* __restrict__ in,
                                                  const float* __restrict__ W,
                                                  const float* __restrict__ bias,
                                                  float* __restrict__ out,
                                                  int Ein, int N, int apply_gelu){
  __shared__ float x_s[BB*64];
  const int tid = threadIdx.x;
  const int e0 = blockIdx.y * 64;
  for(int i = tid; i < BB*64; i += 256){
    const int b = i >> 6, e = i & 63;
    float x = in[b*Ein + e0 + e];
    if(apply_gelu){
      const float x3 = x*x*x;
      x = 0.5f*x*(1.f + tanhf(0.7978845608028654f*(x + 0.044715f*x3)));
    }
    x_s[i] = x;
  }
  __syncthreads();
  const int j = blockIdx.x*256 + tid;
  float acc[BB] = {0,0,0,0,0,0,0,0};
  const float* Wc = W + (size_t)e0 * N + j;
  #pragma unroll 4
  for(int e = 0; e < 64; ++e){
    const float w = Wc[(size_t)e*N];
    #pragma unroll
    for(int b = 0; b < BB; ++b) acc[b] += x_s[b*64+e] * w;
  }
  const float bj = (blockIdx.y == 0) ? bias[j] : 0.f;
  #pragma unroll
  for(int b = 0; b < BB; ++b) atomicAdd(&out[b*N + j], acc[b] + bj);
}

// ---- fused KV-cache copy + flash-decode partials. grid (NCH, B*H), 256 thr ----
__global__ __launch_bounds__(256) void attn_k(const float* __restrict__ Kc,
                                              const float* __restrict__ Vc,
                                              float* __restrict__ outK,
                                              float* __restrict__ outV,
                                              const float* __restrict__ qkv,
                                              const int* __restrict__ past_p,
                                              float* __restrict__ part){
  __shared__ float q_s[DD];
  __shared__ float sc[TCH];
  __shared__ float red[2];
  __shared__ float o_red[4][DD];
  const int tid = threadIdx.x;
  const int chunk = blockIdx.x, bh = blockIdx.y;
  const int b = bh / HH, hh = bh % HH;
  const int past = *past_p;
  const int T = past + 1;
  const int t0 = chunk * TCH;
  if(tid < DD) q_s[tid] = qkv[b*N3E + hh*DD + tid];
  __syncthreads();
  const size_t rowbase = (size_t)(b*HH + hh) * CTX;
  if(tid < TCH){
    // K: copy row + dot with q
    const int t = t0 + tid;
    const size_t off = (rowbase + t) * DD;
    const float* src = (t == past) ? (qkv + b*N3E + EE + hh*DD) : (Kc + off);
    const float4* s4 = reinterpret_cast<const float4*>(src);
    float4* d4 = reinterpret_cast<float4*>(outK + off);
    float dot = 0.f;
    #pragma unroll
    for(int jj = 0; jj < 16; ++jj){
      const float4 kv = s4[jj];
      d4[jj] = kv;
      dot += kv.x*q_s[jj*4+0] + kv.y*q_s[jj*4+1] + kv.z*q_s[jj*4+2] + kv.w*q_s[jj*4+3];
    }
    sc[tid] = (t < T) ? dot * 0.125f : -1e30f;
  } else {
    // V: copy row
    const int t = t0 + (tid - TCH);
    const size_t off = (rowbase + t) * DD;
    const float* src = (t == past) ? (qkv + b*N3E + 2*EE + hh*DD) : (Vc + off);
    const float4* s4 = reinterpret_cast<const float4*>(src);
    float4* d4 = reinterpret_cast<float4*>(outV + off);
    #pragma unroll
    for(int jj = 0; jj < 16; ++jj) d4[jj] = s4[jj];
  }
  __syncthreads();
  if(t0 >= T) return;                       // copy-only tail chunks
  const int nvalid = min(TCH, T - t0);
  if(tid < 64){
    float m = fmaxf(sc[tid], sc[tid + 64]);
    m = wave_reduce_max(m);
    if(tid == 0) red[0] = m;
  }
  __syncthreads();
  const float m_c = red[0];
  if(tid < TCH) sc[tid] = __expf(sc[tid] - m_c);
  __syncthreads();
  if(tid < 64){
    float s = sc[tid] + sc[tid + 64];
    s = wave_reduce_sum(s);
    if(tid == 0) red[1] = s;
  }
  // o partial: 4 waves, lane = d, stripe over t (V rows re-read: L1/L2-resident)
  const int w = tid >> 6, lane = tid & 63;
  float o = 0.f;
  for(int tt = w; tt < nvalid; tt += 4){
    const int t = t0 + tt;
    const float* vsrc = (t == past) ? (qkv + b*N3E + 2*EE + hh*DD)
                                    : (Vc + (rowbase + t) * DD);
    o += sc[tt] * vsrc[lane];
  }
  o_red[w][lane] = o;
  __syncthreads();
  if(tid < 64){
    float* p = part + (size_t)(bh*NCH + chunk) * 66;
    p[2 + tid] = o_red[0][tid] + o_red[1][tid] + o_red[2][tid] + o_red[3][tid];
    if(tid == 0){ p[0] = red[0]; p[1] = red[1]; }
  }
}

// ---- proj GEMV with fused flash-decode combine: blockIdx.y == head ----
__global__ __launch_bounds__(256) void proj_gemv_k(const float* __restrict__ part,
                                                   const int* __restrict__ past_p,
                                                   const float* __restrict__ W,
                                                   const float* __restrict__ bias,
                                                   float* __restrict__ out){
  __shared__ float x_s[BB*64];
  const int tid = threadIdx.x;
  const int hh = blockIdx.y;                // head == e0/64
  const int T = *past_p + 1;
  const int nch = (T + TCH - 1) / TCH;
  for(int i = tid; i < BB*64; i += 256){
    const int b = i >> 6, d = i & 63;
    const float* pb = part + (size_t)((b*HH + hh)*NCH) * 66;
    float M = -1e30f;
    for(int c = 0; c < nch; ++c) M = fmaxf(M, pb[c*66]);
    float S = 0.f, o = 0.f;
    for(int c = 0; c < nch; ++c){
      const float w = __expf(pb[c*66] - M);
      S += pb[c*66 + 1] * w;
      o += pb[c*66 + 2 + d] * w;
    }
    x_s[i] = o / S;
  }
  __syncthreads();
  const int j = blockIdx.x*256 + tid;
  float acc[BB] = {0,0,0,0,0,0,0,0};
  const float* Wc = W + (size_t)(hh*64) * EE + j;
  #pragma unroll 4
  for(int e = 0; e < 64; ++e){
    const float w = Wc[(size_t)e*EE];
    #pragma unroll
    for(int b = 0; b < BB; ++b) acc[b] += x_s[b*64+e] * w;
  }
  const float bj = (blockIdx.y == 0) ? bias[j] : 0.f;
  #pragma unroll
  for(int b = 0; b < BB; ++b) atomicAdd(&out[b*EE + j], acc[b] + bj);
}

// ---- logits with fused final LN: each block recomputes LN(h) into LDS ----
__global__ __launch_bounds__(256) void logits_k(const float* __restrict__ h,
                                                const float* __restrict__ g,
                                                const float* __restrict__ beta,
                                                const float* __restrict__ wte,
                                                float* __restrict__ logits){
  __shared__ float mean_s[BB], rstd_s[BB];
  __shared__ float x_s[BB*EE];
  const int tid = threadIdx.x;
  ln_stats(h, mean_s, rstd_s);
  __syncthreads();
  for(int i = tid; i < BB*EE; i += 256){
    const int b = i / EE, e = i % EE;
    x_s[i] = (h[i] - mean_s[b]) * rstd_s[b] * g[e] + beta[e];
  }
  __syncthreads();
  const int gid = blockIdx.x*256 + tid;
  const int pair = gid >> 1;
  const int v0 = pair * 2;
  if(v0 >= VV) return;
  const int half = gid & 1;
  const int e0 = half * 384;
  const float4* ra = reinterpret_cast<const float4*>(wte + (size_t)v0*EE + e0);
  const float4* rb = reinterpret_cast<const float4*>(wte + (size_t)(v0+1)*EE + e0);
  float acca[BB] = {0,0,0,0,0,0,0,0};
  float accb[BB] = {0,0,0,0,0,0,0,0};
  const bool hasb = (v0 + 1) < VV;
  #pragma unroll 2
  for(int j = 0; j < 96; ++j){
    const float4 wa = ra[j];
    const float4 wb = hasb ? rb[j] : make_float4(0.f,0.f,0.f,0.f);
    const int e = e0 + j*4;
    #pragma unroll
    for(int b = 0; b < BB; ++b){
      const float4 xv = *reinterpret_cast<const float4*>(&x_s[b*EE + e]);
      acca[b] += wa.x*xv.x + wa.y*xv.y + wa.z*xv.z + wa.w*xv.w;
      accb[b] += wb.x*xv.x + wb.y*xv.y + wb.z*xv.z + wb.w*xv.w;
    }
  }
  #pragma unroll
  for(int b = 0; b < BB; ++b){
    const float sa = acca[b] + __shfl_xor(acca[b], 1);
    const float sb = accb[b] + __shfl_xor(accb[b], 1);
    if(half == 0){
      logits[(size_t)b*VV + v0] = sa;
      if(hasb) logits[(size_t)b*VV + v0 + 1] = sb;
    }
  }
}

extern "C" void kernel_launch(void* const* d_in, const int* in_sizes, int n_in,
                              void* d_out, int out_size, void* d_ws, size_t ws_size,
                              hipStream_t stream){
  const int*   ids    = (const int*)  d_in[0];
  const float* keyC   = (const float*)d_in[2];
  const float* valC   = (const float*)d_in[3];
  const int*   past_p = (const int*)  d_in[4];
  const float* wte    = (const float*)d_in[5];
  const float* wpe    = (const float*)d_in[6];
  const float* ln1_g  = (const float*)d_in[7];
  const float* ln1_b  = (const float*)d_in[8];
  const float* attn_w = (const float*)d_in[9];
  const float* attn_b = (const float*)d_in[10];
  const float* proj_w = (const float*)d_in[11];
  const float* proj_b = (const float*)d_in[12];
  const float* ln2_g  = (const float*)d_in[13];
  const float* ln2_b  = (const float*)d_in[14];
  const float* fc_w   = (const float*)d_in[15];
  const float* fc_b   = (const float*)d_in[16];
  const float* fc2_w  = (const float*)d_in[17];
  const float* fc2_b  = (const float*)d_in[18];
  const float* lnf_g  = (const float*)d_in[19];
  const float* lnf_b  = (const float*)d_in[20];

  float* logits = (float*)d_out;
  float* outK = logits + (size_t)BB*VV;
  float* outV = outK + (size_t)LL*BB*HH*CTX*DD;

  float* ws      = (float*)d_ws;
  float* h       = ws;                    // 6144
  float* qkv_all = ws + 6144;             // 12*8*2304 = 221184
  float* u_all   = ws + 227328;           // 12*8*3072 = 294912
  float* part    = ws + 522240;           // 96*16*66  = 101376

  embed_k<<<BB, 256, 0, stream>>>(ids, wte, wpe, past_p, h);
  prep_all_k<<<2016, 256, 0, stream>>>(attn_b, fc_b, qkv_all, u_all);

  for(int l = 0; l < LL; ++l){
    const size_t co = (size_t)l * BB * HH * CTX * DD;
    float* qkv = qkv_all + (size_t)l * BB * N3E;
    float* u   = u_all   + (size_t)l * BB * N4E;
    ln_gemv_k<<<dim3(9,12), 256, 0, stream>>>(h, ln1_g + l*EE, ln1_b + l*EE,
                                              attn_w + (size_t)l*EE*N3E, qkv, N3E);
    attn_k<<<dim3(NCH,96), 256, 0, stream>>>(keyC + co, valC + co, outK + co, outV + co,
                                             qkv, past_p, part);
    proj_gemv_k<<<dim3(3,12), 256, 0, stream>>>(part, past_p, proj_w + (size_t)l*EE*EE,
                                                proj_b + l*EE, h);
    ln_gemv_k<<<dim3(12,12), 256, 0, stream>>>(h, ln2_g + l*EE, ln2_b + l*EE,
                                               fc_w + (size_t)l*EE*N4E, u, N4E);
    gemv_acc_k<<<dim3(3,48), 256, 0, stream>>>(u, fc2_w + (size_t)l*N4E*EE,
                                               fc2_b + l*EE, h, N4E, EE, 1);
  }

  logits_k<<<197, 256, 0, stream>>>(h, lnf_g, lnf_b, wte, logits);
}